// Round 3
// baseline (1412.947 us; speedup 1.0000x reference)
//
#include <hip/hip_runtime.h>
#include <hip/hip_bf16.h>
#include <stdint.h>

typedef __attribute__((ext_vector_type(8))) short bf16x8;
typedef __attribute__((ext_vector_type(4))) float f32x4;
typedef __attribute__((ext_vector_type(4))) _Float16 f16x4;
typedef __attribute__((ext_vector_type(4))) unsigned short u16x4;

__device__ __forceinline__ float b2f(unsigned short u){
  union { unsigned int i; float f; } x; x.i = ((unsigned int)u) << 16; return x.f;
}
__device__ __forceinline__ unsigned short f2b(float f){
  union { float f; unsigned int i; } x; x.f = f;
  unsigned int r = x.i + 0x7fffu + ((x.i >> 16) & 1u);
  return (unsigned short)(r >> 16);
}

__device__ __forceinline__ void gld_lds16(const void* g, void* l){
  __builtin_amdgcn_global_load_lds((const __attribute__((address_space(1))) unsigned int*)g,
                                   (__attribute__((address_space(3))) unsigned int*)l,
                                   16, 0, 0);
}

// ---------------- transpose + fp32->bf16: in (R x C) fp32 -> out (C x R) bf16 ----------------
__global__ __launch_bounds__(256) void transpose_k(const float* __restrict__ in,
                                                   unsigned short* __restrict__ out,
                                                   int R, int C){
  __shared__ unsigned short tile[32][33];
  int tx = threadIdx.x & 31, ty = threadIdx.x >> 5;
  int r0 = blockIdx.y * 32, c0 = blockIdx.x * 32;
#pragma unroll
  for (int t = 0; t < 4; ++t)
    tile[ty + t*8][tx] = f2b(in[(size_t)(r0 + ty + t*8) * C + c0 + tx]);
  __syncthreads();
#pragma unroll
  for (int t = 0; t < 4; ++t)
    out[(size_t)(c0 + ty + t*8) * R + r0 + tx] = tile[tx][ty + t*8];
}

// ---------------- ss = silu(t_vec) @ W (1024x2048) + bias -> fp32 ----------------
__global__ __launch_bounds__(256) void ss_k(const float* __restrict__ tvec,
                                            const float* __restrict__ W,
                                            const float* __restrict__ bias,
                                            float* __restrict__ ss){
  int b = blockIdx.y;
  __shared__ float s[1024];
  int tid = threadIdx.x;
#pragma unroll
  for (int t = 0; t < 4; ++t){
    int i = tid + t*256;
    float c = tvec[b*1024 + i];
    s[i] = c / (1.f + __expf(-c));
  }
  __syncthreads();
  int j = blockIdx.x*256 + tid;
  float acc = bias[j];
#pragma unroll 4
  for (int k = 0; k < 1024; ++k)
    acc += s[k] * W[(size_t)k*2048 + j];
  ss[(size_t)b*2048 + j] = acc;
}

// ---------------- adaptive layernorm (fp32 in, bf16 out): per row of H=1024 ----------------
__global__ __launch_bounds__(256) void ada_ln_k(const float* __restrict__ x,
                                                const float* __restrict__ ss,
                                                unsigned short* __restrict__ out,
                                                int L){
  int row = blockIdx.x;
  int b = row / L;
  const float* xr = x + (size_t)row * 1024;
  int tid = threadIdx.x;
  float4 v = *(const float4*)&xr[tid*4];
  float s = v.x + v.y + v.z + v.w;
  __shared__ float red[4];
#pragma unroll
  for (int o = 32; o > 0; o >>= 1) s += __shfl_xor(s, o, 64);
  if ((tid & 63) == 0) red[tid >> 6] = s;
  __syncthreads();
  float mu = (red[0]+red[1]+red[2]+red[3]) * (1.f/1024.f);
  __syncthreads();
  float vs = (v.x-mu)*(v.x-mu) + (v.y-mu)*(v.y-mu) + (v.z-mu)*(v.z-mu) + (v.w-mu)*(v.w-mu);
#pragma unroll
  for (int o = 32; o > 0; o >>= 1) vs += __shfl_xor(vs, o, 64);
  if ((tid & 63) == 0) red[tid >> 6] = vs;
  __syncthreads();
  float var = (red[0]+red[1]+red[2]+red[3]) * (1.f/1024.f);
  float inv = rsqrtf(var + 1e-5f);
  const float* sb = ss + (size_t)b*2048;
  float4 sc = *(const float4*)&sb[tid*4];
  float4 bi = *(const float4*)&sb[1024 + tid*4];
  u16x4 o4;
  o4[0] = f2b((1.f + sc.x) * ((v.x-mu)*inv) + bi.x);
  o4[1] = f2b((1.f + sc.y) * ((v.y-mu)*inv) + bi.y);
  o4[2] = f2b((1.f + sc.z) * ((v.z-mu)*inv) + bi.z);
  o4[3] = f2b((1.f + sc.w) * ((v.w-mu)*inv) + bi.w);
  *(u16x4*)&out[(size_t)row*1024 + tid*4] = o4;
}

// ---------------- GEMM: C(MxN) = A(MxK,bf16) @ BT(NxK,bf16)^T + bias(fp32) ----------------
// mode 0: bf16 out to Cb (stride N)
// mode 1: fp32 out to Cf (stride N) + fp32 residual resf
// mode 2: kv split: col<1024 -> bf16 Cb (stride 1024); col>=1024 -> f16 vT[b][d][l]
__global__ __launch_bounds__(256) void gemm_bt_k(const unsigned short* __restrict__ A,
                                                 const unsigned short* __restrict__ BT,
                                                 const float* __restrict__ bias,
                                                 const float* __restrict__ resf,
                                                 unsigned short* __restrict__ Cb,
                                                 float* __restrict__ Cf,
                                                 _Float16* __restrict__ vT,
                                                 int M, int N, int K, int mode){
  __shared__ __attribute__((aligned(16))) unsigned short As[128*32];
  __shared__ __attribute__((aligned(16))) unsigned short Bs[128*32];
  const int tid = threadIdx.x;
  const int wave = tid >> 6, lane = tid & 63;
  const int lm = lane & 15, quad = lane >> 4;
  const int m0 = blockIdx.y * 128, n0 = blockIdx.x * 128;
  const int wm = (wave >> 1) * 64, wn = (wave & 1) * 64;
  f32x4 acc[4][4];
#pragma unroll
  for (int i = 0; i < 4; ++i)
#pragma unroll
    for (int j = 0; j < 4; ++j) acc[i][j] = (f32x4){0.f,0.f,0.f,0.f};

  const int c0 = tid, c1 = 256 + tid;
  const int r0c = c0 >> 2, k0c = (c0 & 3) * 8;
  const int r1c = c1 >> 2, k1c = (c1 & 3) * 8;

  for (int k0 = 0; k0 < K; k0 += 32){
    __syncthreads();
    gld_lds16(&A[(size_t)(m0 + r0c)*K + k0 + k0c], &As[c0*8]);
    gld_lds16(&A[(size_t)(m0 + r1c)*K + k0 + k1c], &As[c1*8]);
    gld_lds16(&BT[(size_t)(n0 + r0c)*K + k0 + k0c], &Bs[c0*8]);
    gld_lds16(&BT[(size_t)(n0 + r1c)*K + k0 + k1c], &Bs[c1*8]);
    __syncthreads();
    bf16x8 af[4], bfr[4];
#pragma unroll
    for (int i = 0; i < 4; ++i)
      af[i] = *(bf16x8*)&As[(wm + i*16 + lm)*32 + quad*8];
#pragma unroll
    for (int j = 0; j < 4; ++j)
      bfr[j] = *(bf16x8*)&Bs[(wn + j*16 + lm)*32 + quad*8];
#pragma unroll
    for (int i = 0; i < 4; ++i)
#pragma unroll
      for (int j = 0; j < 4; ++j)
        acc[i][j] = __builtin_amdgcn_mfma_f32_16x16x32_bf16(af[i], bfr[j], acc[i][j], 0, 0, 0);
  }

  if (mode == 2 && n0 >= 1024){
    // V columns -> vT[b][d][l] f16, d = col-1024, rows are l (4 consecutive per lane)
#pragma unroll
    for (int j = 0; j < 4; ++j){
      int col = n0 + wn + j*16 + lm;
      int d = col - 1024;
      float bv = bias[col];
#pragma unroll
      for (int i = 0; i < 4; ++i){
        int rowb = m0 + wm + i*16 + quad*4;
        int brow = rowb >> 9, l = rowb & 511;
        f16x4 h4;
#pragma unroll
        for (int p = 0; p < 4; ++p) h4[p] = (_Float16)(acc[i][j][p] + bv);
        *(f16x4*)&vT[((size_t)brow*1024 + d)*512 + l] = h4;
      }
    }
    return;
  }

#pragma unroll
  for (int j = 0; j < 4; ++j){
    int col = n0 + wn + j*16 + lm;
    float bv = bias[col];
#pragma unroll
    for (int i = 0; i < 4; ++i){
#pragma unroll
      for (int p = 0; p < 4; ++p){
        int row = m0 + wm + i*16 + quad*4 + p;
        float v = acc[i][j][p] + bv;
        if (mode == 1){
          Cf[(size_t)row*N + col] = v + resf[(size_t)row*N + col];
        } else {
          Cb[(size_t)row*1024 + col] = f2b(v);   // mode 0 and mode 2 K-half (both stride 1024)
        }
      }
    }
  }
}

// ---------------- attention v2: S^T trick, zero LDS, zero barriers ----------------
// q: (B,2048,1024) bf16; kbuf: (B*512,1024) bf16; vT: (B,1024,512) f16; out bf16
__global__ __launch_bounds__(256, 3) void attn_k(const unsigned short* __restrict__ q,
                                                 const unsigned short* __restrict__ kbuf,
                                                 const _Float16* __restrict__ vT,
                                                 unsigned short* __restrict__ out){
  const int qb = blockIdx.x, h = blockIdx.y, b = blockIdx.z;
  const int tid = threadIdx.x;
  const int wave = tid >> 6, lane = tid & 63;
  const int lm = lane & 15, quad = lane >> 4;
  const int q0 = qb * 64;

  // Q fragments (B-operand of S^T): rows = this wave's 16 q-rows, loaded once
  const unsigned short* qrow = q + ((size_t)b*2048 + q0 + wave*16 + lm)*1024 + h*64;
  bf16x8 qf0 = *(const bf16x8*)&qrow[quad*8];
  bf16x8 qf1 = *(const bf16x8*)&qrow[32 + quad*8];

  // S^T = K @ Q^T: lane holds S[m=lm][l = lt*16 + quad*4 + p]
  f32x4 sacc[32];
#pragma unroll
  for (int t = 0; t < 32; ++t) sacc[t] = (f32x4){0.f,0.f,0.f,0.f};

  const unsigned short* kb = kbuf + ((size_t)b*512)*1024 + h*64;
#pragma unroll 4
  for (int lt = 0; lt < 32; ++lt){
    const unsigned short* krow = kb + (size_t)(lt*16 + lm)*1024;
    bf16x8 kf0 = *(const bf16x8*)&krow[quad*8];
    bf16x8 kf1 = *(const bf16x8*)&krow[32 + quad*8];
    sacc[lt] = __builtin_amdgcn_mfma_f32_16x16x32_bf16(kf0, qf0, sacc[lt], 0, 0, 0);
    sacc[lt] = __builtin_amdgcn_mfma_f32_16x16x32_bf16(kf1, qf1, sacc[lt], 0, 0, 0);
  }

  // softmax over l (in-lane over 128 values, then cross-quad xor 16/32)
  float mx = -1e30f;
#pragma unroll
  for (int t = 0; t < 32; ++t)
#pragma unroll
    for (int p = 0; p < 4; ++p) mx = fmaxf(mx, sacc[t][p]);
  mx = fmaxf(mx, __shfl_xor(mx, 16, 64));
  mx = fmaxf(mx, __shfl_xor(mx, 32, 64));
  const float mscaled = mx * 0.125f;

  float l4 = 0.f;
  f16x4 pf[32];
#pragma unroll
  for (int t = 0; t < 32; ++t){
    float e0 = __expf(sacc[t][0]*0.125f - mscaled);
    float e1 = __expf(sacc[t][1]*0.125f - mscaled);
    float e2 = __expf(sacc[t][2]*0.125f - mscaled);
    float e3 = __expf(sacc[t][3]*0.125f - mscaled);
    l4 += (e0 + e1) + (e2 + e3);
    pf[t] = (f16x4){(_Float16)e0, (_Float16)e1, (_Float16)e2, (_Float16)e3};
  }
  l4 += __shfl_xor(l4, 16, 64);
  l4 += __shfl_xor(l4, 32, 64);
  float rinv = 1.f / l4;

  // O = P @ V via 16x16x16 f16: A-frag = pf (exact S^T C-layout), B-frag from vT
  f32x4 oacc[4];
#pragma unroll
  for (int nt = 0; nt < 4; ++nt) oacc[nt] = (f32x4){0.f,0.f,0.f,0.f};
  const _Float16* vb = vT + ((size_t)b*1024 + h*64)*512;
#pragma unroll 4
  for (int lt = 0; lt < 32; ++lt){
    int lo = lt*16 + quad*4;
#pragma unroll
    for (int nt = 0; nt < 4; ++nt){
      f16x4 vf = *(const f16x4*)&vb[(size_t)(nt*16 + lm)*512 + lo];
      oacc[nt] = __builtin_amdgcn_mfma_f32_16x16x16f16(pf[lt], vf, oacc[nt], 0, 0, 0);
    }
  }

  // denominators: lane's output rows are quad*4+p; rinv lives at lane lm=row
  float rp[4];
#pragma unroll
  for (int p = 0; p < 4; ++p) rp[p] = __shfl(rinv, quad*4 + p, 64);

  const size_t obase = ((size_t)b*2048 + q0 + wave*16) * 1024 + h*64;
#pragma unroll
  for (int nt = 0; nt < 4; ++nt)
#pragma unroll
    for (int p = 0; p < 4; ++p){
      int row = quad*4 + p;
      out[obase + (size_t)row*1024 + nt*16 + lm] = f2b(oacc[nt][p] * rp[p]);
    }
}

extern "C" void kernel_launch(void* const* d_in, const int* in_sizes, int n_in,
                              void* d_out, int out_size, void* d_ws, size_t ws_size,
                              hipStream_t stream){
  const float* x_q  = (const float*)d_in[0];
  const float* x_kv = (const float*)d_in[1];
  const float* tvec = (const float*)d_in[2];
  const float* Wq   = (const float*)d_in[3];
  const float* bq   = (const float*)d_in[4];
  const float* Wkv  = (const float*)d_in[5];
  const float* bkv  = (const float*)d_in[6];
  const float* Wp   = (const float*)d_in[7];
  const float* bp   = (const float*)d_in[8];
  const float* Wssq = (const float*)d_in[9];
  const float* bssq = (const float*)d_in[10];
  const float* Wssk = (const float*)d_in[11];
  const float* bssk = (const float*)d_in[12];

  char* ws = (char*)d_ws;
  float*          ss_q  = (float*)(ws + 0);                    // 64 KB
  float*          ss_kv = (float*)(ws + 65536);                // 64 KB
  unsigned short* xq    = (unsigned short*)(ws + 131072);      // 32 MB bf16; reused as attn out
  unsigned short* xkv   = (unsigned short*)(ws + 33685504);    // 8 MB bf16
  unsigned short* qbuf  = (unsigned short*)(ws + 42074112);    // 32 MB bf16
  unsigned short* kbuf  = (unsigned short*)(ws + 75628544);    // 8 MB bf16
  _Float16*       vTbuf = (_Float16*)     (ws + 84017152);     // 8 MB f16
  unsigned short* WqT   = (unsigned short*)(ws + 92405760);    // 2 MB bf16
  unsigned short* WkvT  = (unsigned short*)(ws + 94502912);    // 4 MB bf16
  unsigned short* WpT   = (unsigned short*)(ws + 98697216);    // 2 MB bf16

  dim3 blk(256);
  transpose_k<<<dim3(32, 32), blk, 0, stream>>>(Wq,  WqT,  1024, 1024);
  transpose_k<<<dim3(64, 32), blk, 0, stream>>>(Wkv, WkvT, 1024, 2048);
  transpose_k<<<dim3(32, 32), blk, 0, stream>>>(Wp,  WpT,  1024, 1024);

  ss_k<<<dim3(8, 8), blk, 0, stream>>>(tvec, Wssq, bssq, ss_q);
  ss_k<<<dim3(8, 8), blk, 0, stream>>>(tvec, Wssk, bssk, ss_kv);

  ada_ln_k<<<dim3(16384), blk, 0, stream>>>(x_q,  ss_q,  xq,  2048);
  ada_ln_k<<<dim3(4096),  blk, 0, stream>>>(x_kv, ss_kv, xkv, 512);

  gemm_bt_k<<<dim3(8, 128), blk, 0, stream>>>(xq,  WqT,  bq,  nullptr, qbuf, nullptr, nullptr,
                                              16384, 1024, 1024, 0);
  gemm_bt_k<<<dim3(16, 32), blk, 0, stream>>>(xkv, WkvT, bkv, nullptr, kbuf, nullptr, vTbuf,
                                              4096, 2048, 1024, 2);

  attn_k<<<dim3(32, 16, 8), blk, 0, stream>>>(qbuf, kbuf, vTbuf, xq);

  gemm_bt_k<<<dim3(8, 128), blk, 0, stream>>>(xq, WpT, bp, x_q, nullptr, (float*)d_out, nullptr,
                                              16384, 1024, 1024, 1);
}

// Round 5
// 958.600 us; speedup vs baseline: 1.4740x; 1.4740x over previous
//
#include <hip/hip_runtime.h>
#include <hip/hip_bf16.h>
#include <stdint.h>

typedef __attribute__((ext_vector_type(8))) short bf16x8;
typedef __attribute__((ext_vector_type(4))) float f32x4;
typedef __attribute__((ext_vector_type(4))) _Float16 f16x4;
typedef __attribute__((ext_vector_type(4))) unsigned short u16x4;

__device__ __forceinline__ float b2f(unsigned short u){
  union { unsigned int i; float f; } x; x.i = ((unsigned int)u) << 16; return x.f;
}
__device__ __forceinline__ unsigned short f2b(float f){
  union { float f; unsigned int i; } x; x.f = f;
  unsigned int r = x.i + 0x7fffu + ((x.i >> 16) & 1u);
  return (unsigned short)(r >> 16);
}

__device__ __forceinline__ void gld_lds16(const void* g, void* l){
  __builtin_amdgcn_global_load_lds((const __attribute__((address_space(1))) unsigned int*)g,
                                   (__attribute__((address_space(3))) unsigned int*)l,
                                   16, 0, 0);
}

// ---------------- transpose + fp32->bf16: in (R x C) fp32 -> out (C x R) bf16 ----------------
__global__ __launch_bounds__(256) void transpose_k(const float* __restrict__ in,
                                                   unsigned short* __restrict__ out,
                                                   int R, int C){
  __shared__ unsigned short tile[32][33];
  int tx = threadIdx.x & 31, ty = threadIdx.x >> 5;
  int r0 = blockIdx.y * 32, c0 = blockIdx.x * 32;
#pragma unroll
  for (int t = 0; t < 4; ++t)
    tile[ty + t*8][tx] = f2b(in[(size_t)(r0 + ty + t*8) * C + c0 + tx]);
  __syncthreads();
#pragma unroll
  for (int t = 0; t < 4; ++t)
    out[(size_t)(c0 + ty + t*8) * R + r0 + tx] = tile[tx][ty + t*8];
}

// ---------------- ss = silu(t_vec) @ W (1024x2048) + bias -> fp32 ----------------
__global__ __launch_bounds__(256) void ss_k(const float* __restrict__ tvec,
                                            const float* __restrict__ W,
                                            const float* __restrict__ bias,
                                            float* __restrict__ ss){
  int b = blockIdx.y;
  __shared__ float s[1024];
  int tid = threadIdx.x;
#pragma unroll
  for (int t = 0; t < 4; ++t){
    int i = tid + t*256;
    float c = tvec[b*1024 + i];
    s[i] = c / (1.f + __expf(-c));
  }
  __syncthreads();
  int j = blockIdx.x*256 + tid;
  float acc = bias[j];
#pragma unroll 4
  for (int k = 0; k < 1024; ++k)
    acc += s[k] * W[(size_t)k*2048 + j];
  ss[(size_t)b*2048 + j] = acc;
}

// ---------------- adaptive layernorm (fp32 in, bf16 out): per row of H=1024 ----------------
__global__ __launch_bounds__(256) void ada_ln_k(const float* __restrict__ x,
                                                const float* __restrict__ ss,
                                                unsigned short* __restrict__ out,
                                                int L){
  int row = blockIdx.x;
  int b = row / L;
  const float* xr = x + (size_t)row * 1024;
  int tid = threadIdx.x;
  float4 v = *(const float4*)&xr[tid*4];
  float s = v.x + v.y + v.z + v.w;
  __shared__ float red[4];
#pragma unroll
  for (int o = 32; o > 0; o >>= 1) s += __shfl_xor(s, o, 64);
  if ((tid & 63) == 0) red[tid >> 6] = s;
  __syncthreads();
  float mu = (red[0]+red[1]+red[2]+red[3]) * (1.f/1024.f);
  __syncthreads();
  float vs = (v.x-mu)*(v.x-mu) + (v.y-mu)*(v.y-mu) + (v.z-mu)*(v.z-mu) + (v.w-mu)*(v.w-mu);
#pragma unroll
  for (int o = 32; o > 0; o >>= 1) vs += __shfl_xor(vs, o, 64);
  if ((tid & 63) == 0) red[tid >> 6] = vs;
  __syncthreads();
  float var = (red[0]+red[1]+red[2]+red[3]) * (1.f/1024.f);
  float inv = rsqrtf(var + 1e-5f);
  const float* sb = ss + (size_t)b*2048;
  float4 sc = *(const float4*)&sb[tid*4];
  float4 bi = *(const float4*)&sb[1024 + tid*4];
  u16x4 o4;
  o4[0] = f2b((1.f + sc.x) * ((v.x-mu)*inv) + bi.x);
  o4[1] = f2b((1.f + sc.y) * ((v.y-mu)*inv) + bi.y);
  o4[2] = f2b((1.f + sc.z) * ((v.z-mu)*inv) + bi.z);
  o4[3] = f2b((1.f + sc.w) * ((v.w-mu)*inv) + bi.w);
  *(u16x4*)&out[(size_t)row*1024 + tid*4] = o4;
}

// ---------------- GEMM: C(MxN) = A(MxK,bf16) @ BT(NxK,bf16)^T + bias(fp32) ----------------
// mode 0: bf16 out to Cb (stride N)
// mode 1: fp32 out to Cf (stride N) + fp32 residual resf
// mode 2: kv split: col<1024 -> bf16 Cb (stride 1024); col>=1024 -> f16 vT[b][d][l]
__global__ __launch_bounds__(256) void gemm_bt_k(const unsigned short* __restrict__ A,
                                                 const unsigned short* __restrict__ BT,
                                                 const float* __restrict__ bias,
                                                 const float* __restrict__ resf,
                                                 unsigned short* __restrict__ Cb,
                                                 float* __restrict__ Cf,
                                                 _Float16* __restrict__ vT,
                                                 int M, int N, int K, int mode){
  __shared__ __attribute__((aligned(16))) unsigned short As[128*32];
  __shared__ __attribute__((aligned(16))) unsigned short Bs[128*32];
  const int tid = threadIdx.x;
  const int wave = tid >> 6, lane = tid & 63;
  const int lm = lane & 15, quad = lane >> 4;
  const int m0 = blockIdx.y * 128, n0 = blockIdx.x * 128;
  const int wm = (wave >> 1) * 64, wn = (wave & 1) * 64;
  f32x4 acc[4][4];
#pragma unroll
  for (int i = 0; i < 4; ++i)
#pragma unroll
    for (int j = 0; j < 4; ++j) acc[i][j] = (f32x4){0.f,0.f,0.f,0.f};

  const int c0 = tid, c1 = 256 + tid;
  const int r0c = c0 >> 2, k0c = (c0 & 3) * 8;
  const int r1c = c1 >> 2, k1c = (c1 & 3) * 8;

  for (int k0 = 0; k0 < K; k0 += 32){
    __syncthreads();
    gld_lds16(&A[(size_t)(m0 + r0c)*K + k0 + k0c], &As[c0*8]);
    gld_lds16(&A[(size_t)(m0 + r1c)*K + k0 + k1c], &As[c1*8]);
    gld_lds16(&BT[(size_t)(n0 + r0c)*K + k0 + k0c], &Bs[c0*8]);
    gld_lds16(&BT[(size_t)(n0 + r1c)*K + k0 + k1c], &Bs[c1*8]);
    __syncthreads();
    bf16x8 af[4], bfr[4];
#pragma unroll
    for (int i = 0; i < 4; ++i)
      af[i] = *(bf16x8*)&As[(wm + i*16 + lm)*32 + quad*8];
#pragma unroll
    for (int j = 0; j < 4; ++j)
      bfr[j] = *(bf16x8*)&Bs[(wn + j*16 + lm)*32 + quad*8];
#pragma unroll
    for (int i = 0; i < 4; ++i)
#pragma unroll
      for (int j = 0; j < 4; ++j)
        acc[i][j] = __builtin_amdgcn_mfma_f32_16x16x32_bf16(af[i], bfr[j], acc[i][j], 0, 0, 0);
  }

  if (mode == 2 && n0 >= 1024){
    // V columns -> vT[b][d][l] f16, d = col-1024, rows are l (4 consecutive per lane)
#pragma unroll
    for (int j = 0; j < 4; ++j){
      int col = n0 + wn + j*16 + lm;
      int d = col - 1024;
      float bv = bias[col];
#pragma unroll
      for (int i = 0; i < 4; ++i){
        int rowb = m0 + wm + i*16 + quad*4;
        int brow = rowb >> 9, l = rowb & 511;
        f16x4 h4;
#pragma unroll
        for (int p = 0; p < 4; ++p) h4[p] = (_Float16)(acc[i][j][p] + bv);
        *(f16x4*)&vT[((size_t)brow*1024 + d)*512 + l] = h4;
      }
    }
    return;
  }

#pragma unroll
  for (int j = 0; j < 4; ++j){
    int col = n0 + wn + j*16 + lm;
    float bv = bias[col];
#pragma unroll
    for (int i = 0; i < 4; ++i){
#pragma unroll
      for (int p = 0; p < 4; ++p){
        int row = m0 + wm + i*16 + quad*4 + p;
        float v = acc[i][j][p] + bv;
        if (mode == 1){
          Cf[(size_t)row*N + col] = v + resf[(size_t)row*N + col];
        } else {
          Cb[(size_t)row*1024 + col] = f2b(v);   // mode 0 and mode 2 K-half (both stride 1024)
        }
      }
    }
  }
}

// ---------------- attention v4: S^T trick + online softmax, alpha remapped to oacc rows ----------------
// q: (B,2048,1024) bf16; kbuf: (B*512,1024) bf16; vT: (B,1024,512) f16; out bf16
// Per-row softmax state (m_run,l_run) lives in lane-space lm; oacc rows are quad*4+p.
// Every per-row factor applied to oacc MUST be remapped via __shfl(x, quad*4+p).
__global__ __launch_bounds__(256) void attn_k(const unsigned short* __restrict__ q,
                                              const unsigned short* __restrict__ kbuf,
                                              const _Float16* __restrict__ vT,
                                              unsigned short* __restrict__ out){
  const int qb = blockIdx.x, h = blockIdx.y, b = blockIdx.z;
  const int tid = threadIdx.x;
  const int wave = tid >> 6, lane = tid & 63;
  const int lm = lane & 15, quad = lane >> 4;
  const int q0 = qb * 64;

  // Q fragments (B-operand of S^T): this wave's 16 q-rows, loaded once
  const unsigned short* qrow = q + ((size_t)b*2048 + q0 + wave*16 + lm)*1024 + h*64;
  bf16x8 qf0 = *(const bf16x8*)&qrow[quad*8];
  bf16x8 qf1 = *(const bf16x8*)&qrow[32 + quad*8];

  const unsigned short* kb = kbuf + ((size_t)b*512)*1024 + h*64;
  const _Float16*       vb = vT + ((size_t)b*1024 + h*64)*512;

  f32x4 oacc[4];
#pragma unroll
  for (int nt = 0; nt < 4; ++nt) oacc[nt] = (f32x4){0.f,0.f,0.f,0.f};
  float m_run = -1e30f, l_run = 0.f;

  for (int t8 = 0; t8 < 8; ++t8){
    // S^T tile: lane holds S[q=lm][l=(t8*4+s)*16 + quad*4 + p]
    f32x4 sacc[4];
#pragma unroll
    for (int s = 0; s < 4; ++s) sacc[s] = (f32x4){0.f,0.f,0.f,0.f};
#pragma unroll
    for (int s = 0; s < 4; ++s){
      const unsigned short* krow = kb + (size_t)((t8*4 + s)*16 + lm)*1024;
      bf16x8 kf0 = *(const bf16x8*)&krow[quad*8];
      bf16x8 kf1 = *(const bf16x8*)&krow[32 + quad*8];
      sacc[s] = __builtin_amdgcn_mfma_f32_16x16x32_bf16(kf0, qf0, sacc[s], 0, 0, 0);
      sacc[s] = __builtin_amdgcn_mfma_f32_16x16x32_bf16(kf1, qf1, sacc[s], 0, 0, 0);
    }
    // tile max for q-row lm: in-lane over 16 values, then across quads (xor 16/32)
    float tm = -1e30f;
#pragma unroll
    for (int s = 0; s < 4; ++s)
#pragma unroll
      for (int p = 0; p < 4; ++p) tm = fmaxf(tm, sacc[s][p]);
    tm = fmaxf(tm, __shfl_xor(tm, 16, 64));
    tm = fmaxf(tm, __shfl_xor(tm, 32, 64));
    float m_new = fmaxf(m_run, tm * 0.125f);     // 1/sqrt(64)
    float alpha = __expf(m_run - m_new);         // per q-row lm
    m_run = m_new;
    l_run *= alpha;
    // remap alpha from lane-space lm to oacc row-space quad*4+p (lanes 0..15 hold rows 0..15)
    float ap[4];
#pragma unroll
    for (int p = 0; p < 4; ++p) ap[p] = __shfl(alpha, quad*4 + p, 64);
#pragma unroll
    for (int nt = 0; nt < 4; ++nt){
      oacc[nt][0] *= ap[0]; oacc[nt][1] *= ap[1];
      oacc[nt][2] *= ap[2]; oacc[nt][3] *= ap[3];
    }

    f16x4 pf[4];
#pragma unroll
    for (int s = 0; s < 4; ++s){
#pragma unroll
      for (int p = 0; p < 4; ++p){
        float e = __expf(sacc[s][p] * 0.125f - m_new);
        l_run += e;
        pf[s][p] = (_Float16)e;
      }
    }
    // PV: pf is exactly the 16x16x16 f16 A-frag (A[q=lm][k=quad*4+j])
#pragma unroll
    for (int s = 0; s < 4; ++s){
      int lo = (t8*4 + s)*16 + quad*4;
#pragma unroll
      for (int nt = 0; nt < 4; ++nt){
        f16x4 vf = *(const f16x4*)&vb[(size_t)(nt*16 + lm)*512 + lo];
        oacc[nt] = __builtin_amdgcn_mfma_f32_16x16x16f16(pf[s], vf, oacc[nt], 0, 0, 0);
      }
    }
  }

  l_run += __shfl_xor(l_run, 16, 64);
  l_run += __shfl_xor(l_run, 32, 64);
  float rinv = 1.f / l_run;

  // output rows are quad*4+p; rinv for q-row r lives in lane r (lanes 0..15)
  float rp[4];
#pragma unroll
  for (int p = 0; p < 4; ++p) rp[p] = __shfl(rinv, quad*4 + p, 64);

  const size_t obase = ((size_t)b*2048 + q0 + wave*16) * 1024 + h*64;
#pragma unroll
  for (int nt = 0; nt < 4; ++nt)
#pragma unroll
    for (int p = 0; p < 4; ++p){
      int row = quad*4 + p;
      out[obase + (size_t)row*1024 + nt*16 + lm] = f2b(oacc[nt][p] * rp[p]);
    }
}

extern "C" void kernel_launch(void* const* d_in, const int* in_sizes, int n_in,
                              void* d_out, int out_size, void* d_ws, size_t ws_size,
                              hipStream_t stream){
  const float* x_q  = (const float*)d_in[0];
  const float* x_kv = (const float*)d_in[1];
  const float* tvec = (const float*)d_in[2];
  const float* Wq   = (const float*)d_in[3];
  const float* bq   = (const float*)d_in[4];
  const float* Wkv  = (const float*)d_in[5];
  const float* bkv  = (const float*)d_in[6];
  const float* Wp   = (const float*)d_in[7];
  const float* bp   = (const float*)d_in[8];
  const float* Wssq = (const float*)d_in[9];
  const float* bssq = (const float*)d_in[10];
  const float* Wssk = (const float*)d_in[11];
  const float* bssk = (const float*)d_in[12];

  char* ws = (char*)d_ws;
  float*          ss_q  = (float*)(ws + 0);                    // 64 KB
  float*          ss_kv = (float*)(ws + 65536);                // 64 KB
  unsigned short* xq    = (unsigned short*)(ws + 131072);      // 32 MB bf16; reused as attn out
  unsigned short* xkv   = (unsigned short*)(ws + 33685504);    // 8 MB bf16
  unsigned short* qbuf  = (unsigned short*)(ws + 42074112);    // 32 MB bf16
  unsigned short* kbuf  = (unsigned short*)(ws + 75628544);    // 8 MB bf16
  _Float16*       vTbuf = (_Float16*)     (ws + 84017152);     // 8 MB f16
  unsigned short* WqT   = (unsigned short*)(ws + 92405760);    // 2 MB bf16
  unsigned short* WkvT  = (unsigned short*)(ws + 94502912);    // 4 MB bf16
  unsigned short* WpT   = (unsigned short*)(ws + 98697216);    // 2 MB bf16

  dim3 blk(256);
  transpose_k<<<dim3(32, 32), blk, 0, stream>>>(Wq,  WqT,  1024, 1024);
  transpose_k<<<dim3(64, 32), blk, 0, stream>>>(Wkv, WkvT, 1024, 2048);
  transpose_k<<<dim3(32, 32), blk, 0, stream>>>(Wp,  WpT,  1024, 1024);

  ss_k<<<dim3(8, 8), blk, 0, stream>>>(tvec, Wssq, bssq, ss_q);
  ss_k<<<dim3(8, 8), blk, 0, stream>>>(tvec, Wssk, bssk, ss_kv);

  ada_ln_k<<<dim3(16384), blk, 0, stream>>>(x_q,  ss_q,  xq,  2048);
  ada_ln_k<<<dim3(4096),  blk, 0, stream>>>(x_kv, ss_kv, xkv, 512);

  gemm_bt_k<<<dim3(8, 128), blk, 0, stream>>>(xq,  WqT,  bq,  nullptr, qbuf, nullptr, nullptr,
                                              16384, 1024, 1024, 0);
  gemm_bt_k<<<dim3(16, 32), blk, 0, stream>>>(xkv, WkvT, bkv, nullptr, kbuf, nullptr, vTbuf,
                                              4096, 2048, 1024, 2);

  attn_k<<<dim3(32, 16, 8), blk, 0, stream>>>(qbuf, kbuf, vTbuf, xq);

  gemm_bt_k<<<dim3(8, 128), blk, 0, stream>>>(xq, WpT, bp, x_q, nullptr, (float*)d_out, nullptr,
                                              16384, 1024, 1024, 1);
}

// Round 6
// 694.824 us; speedup vs baseline: 2.0335x; 1.3796x over previous
//
#include <hip/hip_runtime.h>
#include <hip/hip_bf16.h>
#include <stdint.h>

typedef __attribute__((ext_vector_type(8))) short bf16x8;
typedef __attribute__((ext_vector_type(4))) float f32x4;
typedef __attribute__((ext_vector_type(4))) _Float16 f16x4;
typedef __attribute__((ext_vector_type(8))) _Float16 f16x8;
typedef __attribute__((ext_vector_type(4))) unsigned short u16x4;

__device__ __forceinline__ float b2f(unsigned short u){
  union { unsigned int i; float f; } x; x.i = ((unsigned int)u) << 16; return x.f;
}
__device__ __forceinline__ unsigned short f2b(float f){
  union { float f; unsigned int i; } x; x.f = f;
  unsigned int r = x.i + 0x7fffu + ((x.i >> 16) & 1u);
  return (unsigned short)(r >> 16);
}

__device__ __forceinline__ void gld_lds16(const void* g, void* l){
  __builtin_amdgcn_global_load_lds((const __attribute__((address_space(1))) unsigned int*)g,
                                   (__attribute__((address_space(3))) unsigned int*)l,
                                   16, 0, 0);
}

// ---------------- transpose + fp32->bf16: in (R x C) fp32 -> out (C x R) bf16 ----------------
__global__ __launch_bounds__(256) void transpose_k(const float* __restrict__ in,
                                                   unsigned short* __restrict__ out,
                                                   int R, int C){
  __shared__ unsigned short tile[32][33];
  int tx = threadIdx.x & 31, ty = threadIdx.x >> 5;
  int r0 = blockIdx.y * 32, c0 = blockIdx.x * 32;
#pragma unroll
  for (int t = 0; t < 4; ++t)
    tile[ty + t*8][tx] = f2b(in[(size_t)(r0 + ty + t*8) * C + c0 + tx]);
  __syncthreads();
#pragma unroll
  for (int t = 0; t < 4; ++t)
    out[(size_t)(c0 + ty + t*8) * R + r0 + tx] = tile[tx][ty + t*8];
}

// ---------------- ss = silu(t_vec) @ W (1024x2048) + bias -> fp32 ----------------
__global__ __launch_bounds__(256) void ss_k(const float* __restrict__ tvec,
                                            const float* __restrict__ W,
                                            const float* __restrict__ bias,
                                            float* __restrict__ ss){
  int b = blockIdx.y;
  __shared__ float s[1024];
  int tid = threadIdx.x;
#pragma unroll
  for (int t = 0; t < 4; ++t){
    int i = tid + t*256;
    float c = tvec[b*1024 + i];
    s[i] = c / (1.f + __expf(-c));
  }
  __syncthreads();
  int j = blockIdx.x*256 + tid;
  float acc = bias[j];
#pragma unroll 4
  for (int k = 0; k < 1024; ++k)
    acc += s[k] * W[(size_t)k*2048 + j];
  ss[(size_t)b*2048 + j] = acc;
}

// ---------------- adaptive layernorm (fp32 in, bf16 out): per row of H=1024 ----------------
__global__ __launch_bounds__(256) void ada_ln_k(const float* __restrict__ x,
                                                const float* __restrict__ ss,
                                                unsigned short* __restrict__ out,
                                                int L){
  int row = blockIdx.x;
  int b = row / L;
  const float* xr = x + (size_t)row * 1024;
  int tid = threadIdx.x;
  float4 v = *(const float4*)&xr[tid*4];
  float s = v.x + v.y + v.z + v.w;
  __shared__ float red[4];
#pragma unroll
  for (int o = 32; o > 0; o >>= 1) s += __shfl_xor(s, o, 64);
  if ((tid & 63) == 0) red[tid >> 6] = s;
  __syncthreads();
  float mu = (red[0]+red[1]+red[2]+red[3]) * (1.f/1024.f);
  __syncthreads();
  float vs = (v.x-mu)*(v.x-mu) + (v.y-mu)*(v.y-mu) + (v.z-mu)*(v.z-mu) + (v.w-mu)*(v.w-mu);
#pragma unroll
  for (int o = 32; o > 0; o >>= 1) vs += __shfl_xor(vs, o, 64);
  if ((tid & 63) == 0) red[tid >> 6] = vs;
  __syncthreads();
  float var = (red[0]+red[1]+red[2]+red[3]) * (1.f/1024.f);
  float inv = rsqrtf(var + 1e-5f);
  const float* sb = ss + (size_t)b*2048;
  float4 sc = *(const float4*)&sb[tid*4];
  float4 bi = *(const float4*)&sb[1024 + tid*4];
  u16x4 o4;
  o4[0] = f2b((1.f + sc.x) * ((v.x-mu)*inv) + bi.x);
  o4[1] = f2b((1.f + sc.y) * ((v.y-mu)*inv) + bi.y);
  o4[2] = f2b((1.f + sc.z) * ((v.z-mu)*inv) + bi.z);
  o4[3] = f2b((1.f + sc.w) * ((v.w-mu)*inv) + bi.w);
  *(u16x4*)&out[(size_t)row*1024 + tid*4] = o4;
}

// ---------------- GEMM: C(MxN) = A(MxK,bf16) @ BT(NxK,bf16)^T + bias(fp32) ----------------
// mode 0: bf16 out to Cb (stride N)
// mode 1: fp32 out to Cf (stride N) + fp32 residual resf
// mode 2: kv split: col<1024 -> bf16 Cb (stride 1024); col>=1024 -> f16 vT[b][d][l]
__global__ __launch_bounds__(256) void gemm_bt_k(const unsigned short* __restrict__ A,
                                                 const unsigned short* __restrict__ BT,
                                                 const float* __restrict__ bias,
                                                 const float* __restrict__ resf,
                                                 unsigned short* __restrict__ Cb,
                                                 float* __restrict__ Cf,
                                                 _Float16* __restrict__ vT,
                                                 int M, int N, int K, int mode){
  __shared__ __attribute__((aligned(16))) unsigned short As[128*32];
  __shared__ __attribute__((aligned(16))) unsigned short Bs[128*32];
  const int tid = threadIdx.x;
  const int wave = tid >> 6, lane = tid & 63;
  const int lm = lane & 15, quad = lane >> 4;
  const int m0 = blockIdx.y * 128, n0 = blockIdx.x * 128;
  const int wm = (wave >> 1) * 64, wn = (wave & 1) * 64;
  f32x4 acc[4][4];
#pragma unroll
  for (int i = 0; i < 4; ++i)
#pragma unroll
    for (int j = 0; j < 4; ++j) acc[i][j] = (f32x4){0.f,0.f,0.f,0.f};

  const int c0 = tid, c1 = 256 + tid;
  const int r0c = c0 >> 2, k0c = (c0 & 3) * 8;
  const int r1c = c1 >> 2, k1c = (c1 & 3) * 8;

  for (int k0 = 0; k0 < K; k0 += 32){
    __syncthreads();
    gld_lds16(&A[(size_t)(m0 + r0c)*K + k0 + k0c], &As[c0*8]);
    gld_lds16(&A[(size_t)(m0 + r1c)*K + k0 + k1c], &As[c1*8]);
    gld_lds16(&BT[(size_t)(n0 + r0c)*K + k0 + k0c], &Bs[c0*8]);
    gld_lds16(&BT[(size_t)(n0 + r1c)*K + k0 + k1c], &Bs[c1*8]);
    __syncthreads();
    bf16x8 af[4], bfr[4];
#pragma unroll
    for (int i = 0; i < 4; ++i)
      af[i] = *(bf16x8*)&As[(wm + i*16 + lm)*32 + quad*8];
#pragma unroll
    for (int j = 0; j < 4; ++j)
      bfr[j] = *(bf16x8*)&Bs[(wn + j*16 + lm)*32 + quad*8];
#pragma unroll
    for (int i = 0; i < 4; ++i)
#pragma unroll
      for (int j = 0; j < 4; ++j)
        acc[i][j] = __builtin_amdgcn_mfma_f32_16x16x32_bf16(af[i], bfr[j], acc[i][j], 0, 0, 0);
  }

  if (mode == 2 && n0 >= 1024){
    // V columns -> vT[b][d][l] f16, d = col-1024, rows are l (4 consecutive per lane)
#pragma unroll
    for (int j = 0; j < 4; ++j){
      int col = n0 + wn + j*16 + lm;
      int d = col - 1024;
      float bv = bias[col];
#pragma unroll
      for (int i = 0; i < 4; ++i){
        int rowb = m0 + wm + i*16 + quad*4;
        int brow = rowb >> 9, l = rowb & 511;
        f16x4 h4;
#pragma unroll
        for (int p = 0; p < 4; ++p) h4[p] = (_Float16)(acc[i][j][p] + bv);
        *(f16x4*)&vT[((size_t)brow*1024 + d)*512 + l] = h4;
      }
    }
    return;
  }

#pragma unroll
  for (int j = 0; j < 4; ++j){
    int col = n0 + wn + j*16 + lm;
    float bv = bias[col];
#pragma unroll
    for (int i = 0; i < 4; ++i){
#pragma unroll
      for (int p = 0; p < 4; ++p){
        int row = m0 + wm + i*16 + quad*4 + p;
        float v = acc[i][j][p] + bv;
        if (mode == 1){
          Cf[(size_t)row*N + col] = v + resf[(size_t)row*N + col];
        } else {
          Cb[(size_t)row*1024 + col] = f2b(v);   // mode 0 and mode 2 K-half (both stride 1024)
        }
      }
    }
  }
}

// ---------------- attention v5: S^T + online softmax + LDS-staged K/V tiles ----------------
// Block = (b, h, 128 q rows); wave = 32 q rows as two 16-row subtiles.
// K tile (64l x 64d bf16) and V^T tile (64d x 64l f16) staged in LDS (stride 72, pad),
// shared by all 4 waves and both subtiles. Frag reads via ds_read (min bank cycles).
__global__ __launch_bounds__(256) void attn_k(const unsigned short* __restrict__ q,
                                              const unsigned short* __restrict__ kbuf,
                                              const _Float16* __restrict__ vT,
                                              unsigned short* __restrict__ out){
  const int qb = blockIdx.x, h = blockIdx.y, b = blockIdx.z;
  const int tid = threadIdx.x;
  const int wave = tid >> 6, lane = tid & 63;
  const int lm = lane & 15, quad = lane >> 4;
  const int q0 = qb * 128;

  __shared__ __attribute__((aligned(16))) unsigned short Ks[64*72];
  __shared__ __attribute__((aligned(16))) _Float16      Vs[64*72];

  // Q B-frags for the wave's two 16-row subtiles (loaded once)
  bf16x8 qf[2][2];
#pragma unroll
  for (int u = 0; u < 2; ++u){
    const unsigned short* qrow = q + ((size_t)b*2048 + q0 + wave*32 + u*16 + lm)*1024 + h*64;
    qf[u][0] = *(const bf16x8*)&qrow[quad*8];
    qf[u][1] = *(const bf16x8*)&qrow[32 + quad*8];
  }

  const unsigned short* kb = kbuf + ((size_t)b*512)*1024 + h*64;
  const _Float16*       vb = vT + ((size_t)b*1024 + h*64)*512;

  f32x4 oacc[2][4];
#pragma unroll
  for (int u = 0; u < 2; ++u)
#pragma unroll
    for (int nt = 0; nt < 4; ++nt) oacc[u][nt] = (f32x4){0.f,0.f,0.f,0.f};
  float m_run[2] = {-1e30f, -1e30f}, l_run[2] = {0.f, 0.f};

  const int srow = tid >> 3, scol = (tid & 7) * 8;   // 32 rows x 64 cols per 256-thread round

  for (int kt = 0; kt < 8; ++kt){
    const int l0 = kt * 64;
    __syncthreads();
#pragma unroll
    for (int r = 0; r < 2; ++r){
      int row = r*32 + srow;
      *(bf16x8*)&Ks[row*72 + scol] = *(const bf16x8*)&kb[(size_t)(l0 + row)*1024 + scol];
      *(f16x8*)&Vs[row*72 + scol]  = *(const f16x8*)&vb[(size_t)row*512 + l0 + scol];
    }
    __syncthreads();

    // S^T subtiles: lane holds S[q=lm][l = l0 + s*16 + quad*4 + p]
    f32x4 sacc[2][4];
#pragma unroll
    for (int u = 0; u < 2; ++u)
#pragma unroll
      for (int s = 0; s < 4; ++s) sacc[u][s] = (f32x4){0.f,0.f,0.f,0.f};
#pragma unroll
    for (int s = 0; s < 4; ++s){
      bf16x8 kf0 = *(bf16x8*)&Ks[(s*16 + lm)*72 + quad*8];
      bf16x8 kf1 = *(bf16x8*)&Ks[(s*16 + lm)*72 + 32 + quad*8];
#pragma unroll
      for (int u = 0; u < 2; ++u){
        sacc[u][s] = __builtin_amdgcn_mfma_f32_16x16x32_bf16(kf0, qf[u][0], sacc[u][s], 0, 0, 0);
        sacc[u][s] = __builtin_amdgcn_mfma_f32_16x16x32_bf16(kf1, qf[u][1], sacc[u][s], 0, 0, 0);
      }
    }

    // online softmax per subtile (state in lane-space lm; oacc rows are quad*4+p)
    f16x4 pf[2][4];
#pragma unroll
    for (int u = 0; u < 2; ++u){
      float tm = -1e30f;
#pragma unroll
      for (int s = 0; s < 4; ++s)
#pragma unroll
        for (int p = 0; p < 4; ++p) tm = fmaxf(tm, sacc[u][s][p]);
      tm = fmaxf(tm, __shfl_xor(tm, 16, 64));
      tm = fmaxf(tm, __shfl_xor(tm, 32, 64));
      float m_new = fmaxf(m_run[u], tm * 0.125f);   // 1/sqrt(64)
      float alpha = __expf(m_run[u] - m_new);
      m_run[u] = m_new;
      l_run[u] *= alpha;
      float ap[4];
#pragma unroll
      for (int p = 0; p < 4; ++p) ap[p] = __shfl(alpha, quad*4 + p, 64);
#pragma unroll
      for (int nt = 0; nt < 4; ++nt){
        oacc[u][nt][0] *= ap[0]; oacc[u][nt][1] *= ap[1];
        oacc[u][nt][2] *= ap[2]; oacc[u][nt][3] *= ap[3];
      }
#pragma unroll
      for (int s = 0; s < 4; ++s)
#pragma unroll
        for (int p = 0; p < 4; ++p){
          float e = __expf(sacc[u][s][p] * 0.125f - m_new);
          l_run[u] += e;
          pf[u][s][p] = (_Float16)e;
        }
    }

    // PV: V B-frags shared across subtiles
#pragma unroll
    for (int s = 0; s < 4; ++s){
#pragma unroll
      for (int nt = 0; nt < 4; ++nt){
        f16x4 vf = *(const f16x4*)&Vs[(size_t)(nt*16 + lm)*72 + s*16 + quad*4];
#pragma unroll
        for (int u = 0; u < 2; ++u)
          oacc[u][nt] = __builtin_amdgcn_mfma_f32_16x16x16f16(pf[u][s], vf, oacc[u][nt], 0, 0, 0);
      }
    }
  }

#pragma unroll
  for (int u = 0; u < 2; ++u){
    float lr = l_run[u];
    lr += __shfl_xor(lr, 16, 64);
    lr += __shfl_xor(lr, 32, 64);
    float rinv = 1.f / lr;
    float rp[4];
#pragma unroll
    for (int p = 0; p < 4; ++p) rp[p] = __shfl(rinv, quad*4 + p, 64);
    const size_t obase = ((size_t)b*2048 + q0 + wave*32 + u*16) * 1024 + h*64;
#pragma unroll
    for (int nt = 0; nt < 4; ++nt)
#pragma unroll
      for (int p = 0; p < 4; ++p){
        int row = quad*4 + p;
        out[obase + (size_t)row*1024 + nt*16 + lm] = f2b(oacc[u][nt][p] * rp[p]);
      }
  }
}

extern "C" void kernel_launch(void* const* d_in, const int* in_sizes, int n_in,
                              void* d_out, int out_size, void* d_ws, size_t ws_size,
                              hipStream_t stream){
  const float* x_q  = (const float*)d_in[0];
  const float* x_kv = (const float*)d_in[1];
  const float* tvec = (const float*)d_in[2];
  const float* Wq   = (const float*)d_in[3];
  const float* bq   = (const float*)d_in[4];
  const float* Wkv  = (const float*)d_in[5];
  const float* bkv  = (const float*)d_in[6];
  const float* Wp   = (const float*)d_in[7];
  const float* bp   = (const float*)d_in[8];
  const float* Wssq = (const float*)d_in[9];
  const float* bssq = (const float*)d_in[10];
  const float* Wssk = (const float*)d_in[11];
  const float* bssk = (const float*)d_in[12];

  char* ws = (char*)d_ws;
  float*          ss_q  = (float*)(ws + 0);                    // 64 KB
  float*          ss_kv = (float*)(ws + 65536);                // 64 KB
  unsigned short* xq    = (unsigned short*)(ws + 131072);      // 32 MB bf16; reused as attn out
  unsigned short* xkv   = (unsigned short*)(ws + 33685504);    // 8 MB bf16
  unsigned short* qbuf  = (unsigned short*)(ws + 42074112);    // 32 MB bf16
  unsigned short* kbuf  = (unsigned short*)(ws + 75628544);    // 8 MB bf16
  _Float16*       vTbuf = (_Float16*)     (ws + 84017152);     // 8 MB f16
  unsigned short* WqT   = (unsigned short*)(ws + 92405760);    // 2 MB bf16
  unsigned short* WkvT  = (unsigned short*)(ws + 94502912);    // 4 MB bf16
  unsigned short* WpT   = (unsigned short*)(ws + 98697216);    // 2 MB bf16

  dim3 blk(256);
  transpose_k<<<dim3(32, 32), blk, 0, stream>>>(Wq,  WqT,  1024, 1024);
  transpose_k<<<dim3(64, 32), blk, 0, stream>>>(Wkv, WkvT, 1024, 2048);
  transpose_k<<<dim3(32, 32), blk, 0, stream>>>(Wp,  WpT,  1024, 1024);

  ss_k<<<dim3(8, 8), blk, 0, stream>>>(tvec, Wssq, bssq, ss_q);
  ss_k<<<dim3(8, 8), blk, 0, stream>>>(tvec, Wssk, bssk, ss_kv);

  ada_ln_k<<<dim3(16384), blk, 0, stream>>>(x_q,  ss_q,  xq,  2048);
  ada_ln_k<<<dim3(4096),  blk, 0, stream>>>(x_kv, ss_kv, xkv, 512);

  gemm_bt_k<<<dim3(8, 128), blk, 0, stream>>>(xq,  WqT,  bq,  nullptr, qbuf, nullptr, nullptr,
                                              16384, 1024, 1024, 0);
  gemm_bt_k<<<dim3(16, 32), blk, 0, stream>>>(xkv, WkvT, bkv, nullptr, kbuf, nullptr, vTbuf,
                                              4096, 2048, 1024, 2);

  attn_k<<<dim3(16, 16, 8), blk, 0, stream>>>(qbuf, kbuf, vTbuf, xq);

  gemm_bt_k<<<dim3(8, 128), blk, 0, stream>>>(xq, WpT, bp, x_q, nullptr, (float*)d_out, nullptr,
                                              16384, 1024, 1024, 1);
}

// Round 7
// 447.615 us; speedup vs baseline: 3.1566x; 1.5523x over previous
//
#include <hip/hip_runtime.h>
#include <hip/hip_bf16.h>
#include <stdint.h>

typedef __attribute__((ext_vector_type(8))) short bf16x8;
typedef __attribute__((ext_vector_type(4))) float f32x4;
typedef __attribute__((ext_vector_type(4))) _Float16 f16x4;
typedef __attribute__((ext_vector_type(8))) _Float16 f16x8;
typedef __attribute__((ext_vector_type(4))) unsigned short u16x4;

__device__ __forceinline__ float b2f(unsigned short u){
  union { unsigned int i; float f; } x; x.i = ((unsigned int)u) << 16; return x.f;
}
__device__ __forceinline__ unsigned short f2b(float f){
  union { float f; unsigned int i; } x; x.f = f;
  unsigned int r = x.i + 0x7fffu + ((x.i >> 16) & 1u);
  return (unsigned short)(r >> 16);
}

__device__ __forceinline__ void gld_lds16(const void* g, void* l){
  __builtin_amdgcn_global_load_lds((const __attribute__((address_space(1))) unsigned int*)g,
                                   (__attribute__((address_space(3))) unsigned int*)l,
                                   16, 0, 0);
}

// ---------------- transpose + fp32->bf16: in (R x C) fp32 -> out (C x R) bf16 ----------------
__global__ __launch_bounds__(256) void transpose_k(const float* __restrict__ in,
                                                   unsigned short* __restrict__ out,
                                                   int R, int C){
  __shared__ unsigned short tile[32][33];
  int tx = threadIdx.x & 31, ty = threadIdx.x >> 5;
  int r0 = blockIdx.y * 32, c0 = blockIdx.x * 32;
#pragma unroll
  for (int t = 0; t < 4; ++t)
    tile[ty + t*8][tx] = f2b(in[(size_t)(r0 + ty + t*8) * C + c0 + tx]);
  __syncthreads();
#pragma unroll
  for (int t = 0; t < 4; ++t)
    out[(size_t)(c0 + ty + t*8) * R + r0 + tx] = tile[tx][ty + t*8];
}

// ---------------- ss init: ss[which][b][j] = bias_which[j] ----------------
__global__ __launch_bounds__(256) void ss_init_k(const float* __restrict__ bssq,
                                                 const float* __restrict__ bssk,
                                                 float* __restrict__ ss_q,
                                                 float* __restrict__ ss_kv){
  int idx = blockIdx.x*256 + threadIdx.x;          // 0..32767
  int which = idx >> 14, rem = idx & 16383;
  int j = rem & 2047;
  if (which) ss_kv[rem] = bssk[j];
  else       ss_q[rem]  = bssq[j];
}

// ---------------- ss main: ss[which][b][col] += sum_k silu(c[b][k]) * W[k][col] ----------------
// grid (8 col-tiles of 256, 16 k-splits of 64, 2 weights); W read exactly once.
__global__ __launch_bounds__(256) void ss2_k(const float* __restrict__ tvec,
                                             const float* __restrict__ Wssq,
                                             const float* __restrict__ Wssk,
                                             float* __restrict__ ss_q,
                                             float* __restrict__ ss_kv){
  const int which = blockIdx.z;
  const float* W = which ? Wssk : Wssq;
  float* ss = which ? ss_kv : ss_q;
  const int col = blockIdx.x*256 + threadIdx.x;
  const int k0 = blockIdx.y*64;

  __shared__ float sl[8][64];
  int idx = threadIdx.x;
#pragma unroll
  for (int t = 0; t < 2; ++t){
    int i = idx + t*256;                            // 0..511 -> b=i>>6, k=i&63
    int b = i >> 6, k = i & 63;
    float c = tvec[b*1024 + k0 + k];
    sl[b][k] = c / (1.f + __expf(-c));
  }
  __syncthreads();

  float acc[8] = {0.f,0.f,0.f,0.f,0.f,0.f,0.f,0.f};
#pragma unroll 8
  for (int k = 0; k < 64; ++k){
    float w = W[(size_t)(k0 + k)*2048 + col];
#pragma unroll
    for (int b = 0; b < 8; ++b) acc[b] += sl[b][k] * w;
  }
#pragma unroll
  for (int b = 0; b < 8; ++b)
    atomicAdd(&ss[b*2048 + col], acc[b]);
}

// ---------------- adaptive layernorm (fp32 in, bf16 out): per row of H=1024 ----------------
__global__ __launch_bounds__(256) void ada_ln_k(const float* __restrict__ x,
                                                const float* __restrict__ ss,
                                                unsigned short* __restrict__ out,
                                                int L){
  int row = blockIdx.x;
  int b = row / L;
  const float* xr = x + (size_t)row * 1024;
  int tid = threadIdx.x;
  float4 v = *(const float4*)&xr[tid*4];
  float s = v.x + v.y + v.z + v.w;
  __shared__ float red[4];
#pragma unroll
  for (int o = 32; o > 0; o >>= 1) s += __shfl_xor(s, o, 64);
  if ((tid & 63) == 0) red[tid >> 6] = s;
  __syncthreads();
  float mu = (red[0]+red[1]+red[2]+red[3]) * (1.f/1024.f);
  __syncthreads();
  float vs = (v.x-mu)*(v.x-mu) + (v.y-mu)*(v.y-mu) + (v.z-mu)*(v.z-mu) + (v.w-mu)*(v.w-mu);
#pragma unroll
  for (int o = 32; o > 0; o >>= 1) vs += __shfl_xor(vs, o, 64);
  if ((tid & 63) == 0) red[tid >> 6] = vs;
  __syncthreads();
  float var = (red[0]+red[1]+red[2]+red[3]) * (1.f/1024.f);
  float inv = rsqrtf(var + 1e-5f);
  const float* sb = ss + (size_t)b*2048;
  float4 sc = *(const float4*)&sb[tid*4];
  float4 bi = *(const float4*)&sb[1024 + tid*4];
  u16x4 o4;
  o4[0] = f2b((1.f + sc.x) * ((v.x-mu)*inv) + bi.x);
  o4[1] = f2b((1.f + sc.y) * ((v.y-mu)*inv) + bi.y);
  o4[2] = f2b((1.f + sc.z) * ((v.z-mu)*inv) + bi.z);
  o4[3] = f2b((1.f + sc.w) * ((v.w-mu)*inv) + bi.w);
  *(u16x4*)&out[(size_t)row*1024 + tid*4] = o4;
}

// ---------------- GEMM: C(MxN) = A(MxK,bf16) @ BT(NxK,bf16)^T + bias(fp32) ----------------
// mode 0: bf16 out to Cb (stride N)
// mode 1: fp32 out to Cf (stride N) + fp32 residual resf
// mode 2: kv split: col<1024 -> bf16 Cb (stride 1024); col>=1024 -> f16 vT[b][d][l]
__global__ __launch_bounds__(256) void gemm_bt_k(const unsigned short* __restrict__ A,
                                                 const unsigned short* __restrict__ BT,
                                                 const float* __restrict__ bias,
                                                 const float* __restrict__ resf,
                                                 unsigned short* __restrict__ Cb,
                                                 float* __restrict__ Cf,
                                                 _Float16* __restrict__ vT,
                                                 int M, int N, int K, int mode){
  __shared__ __attribute__((aligned(16))) unsigned short As[128*32];
  __shared__ __attribute__((aligned(16))) unsigned short Bs[128*32];
  const int tid = threadIdx.x;
  const int wave = tid >> 6, lane = tid & 63;
  const int lm = lane & 15, quad = lane >> 4;
  const int m0 = blockIdx.y * 128, n0 = blockIdx.x * 128;
  const int wm = (wave >> 1) * 64, wn = (wave & 1) * 64;
  f32x4 acc[4][4];
#pragma unroll
  for (int i = 0; i < 4; ++i)
#pragma unroll
    for (int j = 0; j < 4; ++j) acc[i][j] = (f32x4){0.f,0.f,0.f,0.f};

  const int c0 = tid, c1 = 256 + tid;
  const int r0c = c0 >> 2, k0c = (c0 & 3) * 8;
  const int r1c = c1 >> 2, k1c = (c1 & 3) * 8;

  for (int k0 = 0; k0 < K; k0 += 32){
    __syncthreads();
    gld_lds16(&A[(size_t)(m0 + r0c)*K + k0 + k0c], &As[c0*8]);
    gld_lds16(&A[(size_t)(m0 + r1c)*K + k0 + k1c], &As[c1*8]);
    gld_lds16(&BT[(size_t)(n0 + r0c)*K + k0 + k0c], &Bs[c0*8]);
    gld_lds16(&BT[(size_t)(n0 + r1c)*K + k0 + k1c], &Bs[c1*8]);
    __syncthreads();
    bf16x8 af[4], bfr[4];
#pragma unroll
    for (int i = 0; i < 4; ++i)
      af[i] = *(bf16x8*)&As[(wm + i*16 + lm)*32 + quad*8];
#pragma unroll
    for (int j = 0; j < 4; ++j)
      bfr[j] = *(bf16x8*)&Bs[(wn + j*16 + lm)*32 + quad*8];
#pragma unroll
    for (int i = 0; i < 4; ++i)
#pragma unroll
      for (int j = 0; j < 4; ++j)
        acc[i][j] = __builtin_amdgcn_mfma_f32_16x16x32_bf16(af[i], bfr[j], acc[i][j], 0, 0, 0);
  }

  if (mode == 2 && n0 >= 1024){
    // V columns -> vT[b][d][l] f16, d = col-1024, rows are l (4 consecutive per lane)
#pragma unroll
    for (int j = 0; j < 4; ++j){
      int col = n0 + wn + j*16 + lm;
      int d = col - 1024;
      float bv = bias[col];
#pragma unroll
      for (int i = 0; i < 4; ++i){
        int rowb = m0 + wm + i*16 + quad*4;
        int brow = rowb >> 9, l = rowb & 511;
        f16x4 h4;
#pragma unroll
        for (int p = 0; p < 4; ++p) h4[p] = (_Float16)(acc[i][j][p] + bv);
        *(f16x4*)&vT[((size_t)brow*1024 + d)*512 + l] = h4;
      }
    }
    return;
  }

#pragma unroll
  for (int j = 0; j < 4; ++j){
    int col = n0 + wn + j*16 + lm;
    float bv = bias[col];
#pragma unroll
    for (int i = 0; i < 4; ++i){
#pragma unroll
      for (int p = 0; p < 4; ++p){
        int row = m0 + wm + i*16 + quad*4 + p;
        float v = acc[i][j][p] + bv;
        if (mode == 1){
          Cf[(size_t)row*N + col] = v + resf[(size_t)row*N + col];
        } else {
          Cb[(size_t)row*1024 + col] = f2b(v);   // mode 0 and mode 2 K-half (both stride 1024)
        }
      }
    }
  }
}

// ---------------- attention v5: S^T + online softmax + LDS-staged K/V tiles ----------------
__global__ __launch_bounds__(256) void attn_k(const unsigned short* __restrict__ q,
                                              const unsigned short* __restrict__ kbuf,
                                              const _Float16* __restrict__ vT,
                                              unsigned short* __restrict__ out){
  const int qb = blockIdx.x, h = blockIdx.y, b = blockIdx.z;
  const int tid = threadIdx.x;
  const int wave = tid >> 6, lane = tid & 63;
  const int lm = lane & 15, quad = lane >> 4;
  const int q0 = qb * 128;

  __shared__ __attribute__((aligned(16))) unsigned short Ks[64*72];
  __shared__ __attribute__((aligned(16))) _Float16      Vs[64*72];

  bf16x8 qf[2][2];
#pragma unroll
  for (int u = 0; u < 2; ++u){
    const unsigned short* qrow = q + ((size_t)b*2048 + q0 + wave*32 + u*16 + lm)*1024 + h*64;
    qf[u][0] = *(const bf16x8*)&qrow[quad*8];
    qf[u][1] = *(const bf16x8*)&qrow[32 + quad*8];
  }

  const unsigned short* kb = kbuf + ((size_t)b*512)*1024 + h*64;
  const _Float16*       vb = vT + ((size_t)b*1024 + h*64)*512;

  f32x4 oacc[2][4];
#pragma unroll
  for (int u = 0; u < 2; ++u)
#pragma unroll
    for (int nt = 0; nt < 4; ++nt) oacc[u][nt] = (f32x4){0.f,0.f,0.f,0.f};
  float m_run[2] = {-1e30f, -1e30f}, l_run[2] = {0.f, 0.f};

  const int srow = tid >> 3, scol = (tid & 7) * 8;

  for (int kt = 0; kt < 8; ++kt){
    const int l0 = kt * 64;
    __syncthreads();
#pragma unroll
    for (int r = 0; r < 2; ++r){
      int row = r*32 + srow;
      *(bf16x8*)&Ks[row*72 + scol] = *(const bf16x8*)&kb[(size_t)(l0 + row)*1024 + scol];
      *(f16x8*)&Vs[row*72 + scol]  = *(const f16x8*)&vb[(size_t)row*512 + l0 + scol];
    }
    __syncthreads();

    f32x4 sacc[2][4];
#pragma unroll
    for (int u = 0; u < 2; ++u)
#pragma unroll
      for (int s = 0; s < 4; ++s) sacc[u][s] = (f32x4){0.f,0.f,0.f,0.f};
#pragma unroll
    for (int s = 0; s < 4; ++s){
      bf16x8 kf0 = *(bf16x8*)&Ks[(s*16 + lm)*72 + quad*8];
      bf16x8 kf1 = *(bf16x8*)&Ks[(s*16 + lm)*72 + 32 + quad*8];
#pragma unroll
      for (int u = 0; u < 2; ++u){
        sacc[u][s] = __builtin_amdgcn_mfma_f32_16x16x32_bf16(kf0, qf[u][0], sacc[u][s], 0, 0, 0);
        sacc[u][s] = __builtin_amdgcn_mfma_f32_16x16x32_bf16(kf1, qf[u][1], sacc[u][s], 0, 0, 0);
      }
    }

    f16x4 pf[2][4];
#pragma unroll
    for (int u = 0; u < 2; ++u){
      float tm = -1e30f;
#pragma unroll
      for (int s = 0; s < 4; ++s)
#pragma unroll
        for (int p = 0; p < 4; ++p) tm = fmaxf(tm, sacc[u][s][p]);
      tm = fmaxf(tm, __shfl_xor(tm, 16, 64));
      tm = fmaxf(tm, __shfl_xor(tm, 32, 64));
      float m_new = fmaxf(m_run[u], tm * 0.125f);
      float alpha = __expf(m_run[u] - m_new);
      m_run[u] = m_new;
      l_run[u] *= alpha;
      float ap[4];
#pragma unroll
      for (int p = 0; p < 4; ++p) ap[p] = __shfl(alpha, quad*4 + p, 64);
#pragma unroll
      for (int nt = 0; nt < 4; ++nt){
        oacc[u][nt][0] *= ap[0]; oacc[u][nt][1] *= ap[1];
        oacc[u][nt][2] *= ap[2]; oacc[u][nt][3] *= ap[3];
      }
#pragma unroll
      for (int s = 0; s < 4; ++s)
#pragma unroll
        for (int p = 0; p < 4; ++p){
          float e = __expf(sacc[u][s][p] * 0.125f - m_new);
          l_run[u] += e;
          pf[u][s][p] = (_Float16)e;
        }
    }

#pragma unroll
    for (int s = 0; s < 4; ++s){
#pragma unroll
      for (int nt = 0; nt < 4; ++nt){
        f16x4 vf = *(const f16x4*)&Vs[(size_t)(nt*16 + lm)*72 + s*16 + quad*4];
#pragma unroll
        for (int u = 0; u < 2; ++u)
          oacc[u][nt] = __builtin_amdgcn_mfma_f32_16x16x16f16(pf[u][s], vf, oacc[u][nt], 0, 0, 0);
      }
    }
  }

#pragma unroll
  for (int u = 0; u < 2; ++u){
    float lr = l_run[u];
    lr += __shfl_xor(lr, 16, 64);
    lr += __shfl_xor(lr, 32, 64);
    float rinv = 1.f / lr;
    float rp[4];
#pragma unroll
    for (int p = 0; p < 4; ++p) rp[p] = __shfl(rinv, quad*4 + p, 64);
    const size_t obase = ((size_t)b*2048 + q0 + wave*32 + u*16) * 1024 + h*64;
#pragma unroll
    for (int nt = 0; nt < 4; ++nt)
#pragma unroll
      for (int p = 0; p < 4; ++p){
        int row = quad*4 + p;
        out[obase + (size_t)row*1024 + nt*16 + lm] = f2b(oacc[u][nt][p] * rp[p]);
      }
  }
}

extern "C" void kernel_launch(void* const* d_in, const int* in_sizes, int n_in,
                              void* d_out, int out_size, void* d_ws, size_t ws_size,
                              hipStream_t stream){
  const float* x_q  = (const float*)d_in[0];
  const float* x_kv = (const float*)d_in[1];
  const float* tvec = (const float*)d_in[2];
  const float* Wq   = (const float*)d_in[3];
  const float* bq   = (const float*)d_in[4];
  const float* Wkv  = (const float*)d_in[5];
  const float* bkv  = (const float*)d_in[6];
  const float* Wp   = (const float*)d_in[7];
  const float* bp   = (const float*)d_in[8];
  const float* Wssq = (const float*)d_in[9];
  const float* bssq = (const float*)d_in[10];
  const float* Wssk = (const float*)d_in[11];
  const float* bssk = (const float*)d_in[12];

  char* ws = (char*)d_ws;
  float*          ss_q  = (float*)(ws + 0);                    // 64 KB
  float*          ss_kv = (float*)(ws + 65536);                // 64 KB
  unsigned short* xq    = (unsigned short*)(ws + 131072);      // 32 MB bf16; reused as attn out
  unsigned short* xkv   = (unsigned short*)(ws + 33685504);    // 8 MB bf16
  unsigned short* qbuf  = (unsigned short*)(ws + 42074112);    // 32 MB bf16
  unsigned short* kbuf  = (unsigned short*)(ws + 75628544);    // 8 MB bf16
  _Float16*       vTbuf = (_Float16*)     (ws + 84017152);     // 8 MB f16
  unsigned short* WqT   = (unsigned short*)(ws + 92405760);    // 2 MB bf16
  unsigned short* WkvT  = (unsigned short*)(ws + 94502912);    // 4 MB bf16
  unsigned short* WpT   = (unsigned short*)(ws + 98697216);    // 2 MB bf16

  dim3 blk(256);
  transpose_k<<<dim3(32, 32), blk, 0, stream>>>(Wq,  WqT,  1024, 1024);
  transpose_k<<<dim3(64, 32), blk, 0, stream>>>(Wkv, WkvT, 1024, 2048);
  transpose_k<<<dim3(32, 32), blk, 0, stream>>>(Wp,  WpT,  1024, 1024);

  ss_init_k<<<dim3(128), blk, 0, stream>>>(bssq, bssk, ss_q, ss_kv);
  ss2_k<<<dim3(8, 16, 2), blk, 0, stream>>>(tvec, Wssq, Wssk, ss_q, ss_kv);

  ada_ln_k<<<dim3(16384), blk, 0, stream>>>(x_q,  ss_q,  xq,  2048);
  ada_ln_k<<<dim3(4096),  blk, 0, stream>>>(x_kv, ss_kv, xkv, 512);

  gemm_bt_k<<<dim3(8, 128), blk, 0, stream>>>(xq,  WqT,  bq,  nullptr, qbuf, nullptr, nullptr,
                                              16384, 1024, 1024, 0);
  gemm_bt_k<<<dim3(16, 32), blk, 0, stream>>>(xkv, WkvT, bkv, nullptr, kbuf, nullptr, vTbuf,
                                              4096, 2048, 1024, 2);

  attn_k<<<dim3(16, 16, 8), blk, 0, stream>>>(qbuf, kbuf, vTbuf, xq);

  gemm_bt_k<<<dim3(8, 128), blk, 0, stream>>>(xq, WpT, bp, x_q, nullptr, (float*)d_out, nullptr,
                                              16384, 1024, 1024, 1);
}

// Round 8
// 441.802 us; speedup vs baseline: 3.1981x; 1.0132x over previous
//
#include <hip/hip_runtime.h>
#include <hip/hip_bf16.h>
#include <stdint.h>

typedef __attribute__((ext_vector_type(8))) short bf16x8;
typedef __attribute__((ext_vector_type(4))) float f32x4;
typedef __attribute__((ext_vector_type(4))) _Float16 f16x4;
typedef __attribute__((ext_vector_type(8))) _Float16 f16x8;
typedef __attribute__((ext_vector_type(4))) unsigned short u16x4;

__device__ __forceinline__ float b2f(unsigned short u){
  union { unsigned int i; float f; } x; x.i = ((unsigned int)u) << 16; return x.f;
}
__device__ __forceinline__ unsigned short f2b(float f){
  union { float f; unsigned int i; } x; x.f = f;
  unsigned int r = x.i + 0x7fffu + ((x.i >> 16) & 1u);
  return (unsigned short)(r >> 16);
}

__device__ __forceinline__ void gld_lds16(const void* g, void* l){
  __builtin_amdgcn_global_load_lds((const __attribute__((address_space(1))) unsigned int*)g,
                                   (__attribute__((address_space(3))) unsigned int*)l,
                                   16, 0, 0);
}

// ---------------- transpose + fp32->bf16: in (R x C) fp32 -> out (C x R) bf16 ----------------
__global__ __launch_bounds__(256) void transpose_k(const float* __restrict__ in,
                                                   unsigned short* __restrict__ out,
                                                   int R, int C){
  __shared__ unsigned short tile[32][33];
  int tx = threadIdx.x & 31, ty = threadIdx.x >> 5;
  int r0 = blockIdx.y * 32, c0 = blockIdx.x * 32;
#pragma unroll
  for (int t = 0; t < 4; ++t)
    tile[ty + t*8][tx] = f2b(in[(size_t)(r0 + ty + t*8) * C + c0 + tx]);
  __syncthreads();
#pragma unroll
  for (int t = 0; t < 4; ++t)
    out[(size_t)(c0 + ty + t*8) * R + r0 + tx] = tile[tx][ty + t*8];
}

// ---------------- ss init: ss[which][b][j] = bias_which[j] ----------------
__global__ __launch_bounds__(256) void ss_init_k(const float* __restrict__ bssq,
                                                 const float* __restrict__ bssk,
                                                 float* __restrict__ ss_q,
                                                 float* __restrict__ ss_kv){
  int idx = blockIdx.x*256 + threadIdx.x;          // 0..32767
  int which = idx >> 14, rem = idx & 16383;
  int j = rem & 2047;
  if (which) ss_kv[rem] = bssk[j];
  else       ss_q[rem]  = bssq[j];
}

// ---------------- ss main: ss[which][b][col] += sum_k silu(c[b][k]) * W[k][col] ----------------
__global__ __launch_bounds__(256) void ss2_k(const float* __restrict__ tvec,
                                             const float* __restrict__ Wssq,
                                             const float* __restrict__ Wssk,
                                             float* __restrict__ ss_q,
                                             float* __restrict__ ss_kv){
  const int which = blockIdx.z;
  const float* W = which ? Wssk : Wssq;
  float* ss = which ? ss_kv : ss_q;
  const int col = blockIdx.x*256 + threadIdx.x;
  const int k0 = blockIdx.y*64;

  __shared__ float sl[8][64];
  int idx = threadIdx.x;
#pragma unroll
  for (int t = 0; t < 2; ++t){
    int i = idx + t*256;
    int b = i >> 6, k = i & 63;
    float c = tvec[b*1024 + k0 + k];
    sl[b][k] = c / (1.f + __expf(-c));
  }
  __syncthreads();

  float acc[8] = {0.f,0.f,0.f,0.f,0.f,0.f,0.f,0.f};
#pragma unroll 8
  for (int k = 0; k < 64; ++k){
    float w = W[(size_t)(k0 + k)*2048 + col];
#pragma unroll
    for (int b = 0; b < 8; ++b) acc[b] += sl[b][k] * w;
  }
#pragma unroll
  for (int b = 0; b < 8; ++b)
    atomicAdd(&ss[b*2048 + col], acc[b]);
}

// ---------------- adaptive layernorm (fp32 in, bf16 out): per row of H=1024 ----------------
__global__ __launch_bounds__(256) void ada_ln_k(const float* __restrict__ x,
                                                const float* __restrict__ ss,
                                                unsigned short* __restrict__ out,
                                                int L){
  int row = blockIdx.x;
  int b = row / L;
  const float* xr = x + (size_t)row * 1024;
  int tid = threadIdx.x;
  float4 v = *(const float4*)&xr[tid*4];
  float s = v.x + v.y + v.z + v.w;
  __shared__ float red[4];
#pragma unroll
  for (int o = 32; o > 0; o >>= 1) s += __shfl_xor(s, o, 64);
  if ((tid & 63) == 0) red[tid >> 6] = s;
  __syncthreads();
  float mu = (red[0]+red[1]+red[2]+red[3]) * (1.f/1024.f);
  __syncthreads();
  float vs = (v.x-mu)*(v.x-mu) + (v.y-mu)*(v.y-mu) + (v.z-mu)*(v.z-mu) + (v.w-mu)*(v.w-mu);
#pragma unroll
  for (int o = 32; o > 0; o >>= 1) vs += __shfl_xor(vs, o, 64);
  if ((tid & 63) == 0) red[tid >> 6] = vs;
  __syncthreads();
  float var = (red[0]+red[1]+red[2]+red[3]) * (1.f/1024.f);
  float inv = rsqrtf(var + 1e-5f);
  const float* sb = ss + (size_t)b*2048;
  float4 sc = *(const float4*)&sb[tid*4];
  float4 bi = *(const float4*)&sb[1024 + tid*4];
  u16x4 o4;
  o4[0] = f2b((1.f + sc.x) * ((v.x-mu)*inv) + bi.x);
  o4[1] = f2b((1.f + sc.y) * ((v.y-mu)*inv) + bi.y);
  o4[2] = f2b((1.f + sc.z) * ((v.z-mu)*inv) + bi.z);
  o4[3] = f2b((1.f + sc.w) * ((v.w-mu)*inv) + bi.w);
  *(u16x4*)&out[(size_t)row*1024 + tid*4] = o4;
}

// ---------------- GEMM: C(MxN) = A(MxK,bf16) @ BT(NxK,bf16)^T + bias(fp32) ----------------
// BK=64: 32 MFMAs per barrier pair (halved drain count vs BK=32).
// mode 0: bf16 out to Cb (stride 1024)
// mode 1: fp32 out to Cf (stride N) + fp32 residual resf
// mode 2: kv split: col<1024 -> bf16 Cb (stride 1024); col>=1024 -> f16 vT[b][d][l]
__global__ __launch_bounds__(256) void gemm_bt_k(const unsigned short* __restrict__ A,
                                                 const unsigned short* __restrict__ BT,
                                                 const float* __restrict__ bias,
                                                 const float* __restrict__ resf,
                                                 unsigned short* __restrict__ Cb,
                                                 float* __restrict__ Cf,
                                                 _Float16* __restrict__ vT,
                                                 int M, int N, int K, int mode){
  __shared__ __attribute__((aligned(16))) unsigned short As[128*64];
  __shared__ __attribute__((aligned(16))) unsigned short Bs[128*64];
  const int tid = threadIdx.x;
  const int wave = tid >> 6, lane = tid & 63;
  const int lm = lane & 15, quad = lane >> 4;
  const int m0 = blockIdx.y * 128, n0 = blockIdx.x * 128;
  const int wm = (wave >> 1) * 64, wn = (wave & 1) * 64;
  f32x4 acc[4][4];
#pragma unroll
  for (int i = 0; i < 4; ++i)
#pragma unroll
    for (int j = 0; j < 4; ++j) acc[i][j] = (f32x4){0.f,0.f,0.f,0.f};

  // staging map: c = r*256+tid in [0,1024): row = c>>3, colseg = (c&7)*8
  int rowc[4], colc[4];
#pragma unroll
  for (int r = 0; r < 4; ++r){
    int c = r*256 + tid;
    rowc[r] = c >> 3; colc[r] = (c & 7) * 8;
  }

  for (int k0 = 0; k0 < K; k0 += 64){
    __syncthreads();
#pragma unroll
    for (int r = 0; r < 4; ++r)
      gld_lds16(&A[(size_t)(m0 + rowc[r])*K + k0 + colc[r]], &As[(r*256 + tid)*8]);
#pragma unroll
    for (int r = 0; r < 4; ++r)
      gld_lds16(&BT[(size_t)(n0 + rowc[r])*K + k0 + colc[r]], &Bs[(r*256 + tid)*8]);
    __syncthreads();
#pragma unroll
    for (int ks = 0; ks < 2; ++ks){
      bf16x8 af[4], bfr[4];
#pragma unroll
      for (int i = 0; i < 4; ++i)
        af[i] = *(bf16x8*)&As[(wm + i*16 + lm)*64 + ks*32 + quad*8];
#pragma unroll
      for (int j = 0; j < 4; ++j)
        bfr[j] = *(bf16x8*)&Bs[(wn + j*16 + lm)*64 + ks*32 + quad*8];
#pragma unroll
      for (int i = 0; i < 4; ++i)
#pragma unroll
        for (int j = 0; j < 4; ++j)
          acc[i][j] = __builtin_amdgcn_mfma_f32_16x16x32_bf16(af[i], bfr[j], acc[i][j], 0, 0, 0);
    }
  }

  if (mode == 2 && n0 >= 1024){
#pragma unroll
    for (int j = 0; j < 4; ++j){
      int col = n0 + wn + j*16 + lm;
      int d = col - 1024;
      float bv = bias[col];
#pragma unroll
      for (int i = 0; i < 4; ++i){
        int rowb = m0 + wm + i*16 + quad*4;
        int brow = rowb >> 9, l = rowb & 511;
        f16x4 h4;
#pragma unroll
        for (int p = 0; p < 4; ++p) h4[p] = (_Float16)(acc[i][j][p] + bv);
        *(f16x4*)&vT[((size_t)brow*1024 + d)*512 + l] = h4;
      }
    }
    return;
  }

#pragma unroll
  for (int j = 0; j < 4; ++j){
    int col = n0 + wn + j*16 + lm;
    float bv = bias[col];
#pragma unroll
    for (int i = 0; i < 4; ++i){
#pragma unroll
      for (int p = 0; p < 4; ++p){
        int row = m0 + wm + i*16 + quad*4 + p;
        float v = acc[i][j][p] + bv;
        if (mode == 1){
          Cf[(size_t)row*N + col] = v + resf[(size_t)row*N + col];
        } else {
          Cb[(size_t)row*1024 + col] = f2b(v);
        }
      }
    }
  }
}

// ---------------- attention v5: S^T + online softmax + LDS-staged K/V tiles ----------------
__global__ __launch_bounds__(256) void attn_k(const unsigned short* __restrict__ q,
                                              const unsigned short* __restrict__ kbuf,
                                              const _Float16* __restrict__ vT,
                                              unsigned short* __restrict__ out){
  const int qb = blockIdx.x, h = blockIdx.y, b = blockIdx.z;
  const int tid = threadIdx.x;
  const int wave = tid >> 6, lane = tid & 63;
  const int lm = lane & 15, quad = lane >> 4;
  const int q0 = qb * 128;

  __shared__ __attribute__((aligned(16))) unsigned short Ks[64*72];
  __shared__ __attribute__((aligned(16))) _Float16      Vs[64*72];

  bf16x8 qf[2][2];
#pragma unroll
  for (int u = 0; u < 2; ++u){
    const unsigned short* qrow = q + ((size_t)b*2048 + q0 + wave*32 + u*16 + lm)*1024 + h*64;
    qf[u][0] = *(const bf16x8*)&qrow[quad*8];
    qf[u][1] = *(const bf16x8*)&qrow[32 + quad*8];
  }

  const unsigned short* kb = kbuf + ((size_t)b*512)*1024 + h*64;
  const _Float16*       vb = vT + ((size_t)b*1024 + h*64)*512;

  f32x4 oacc[2][4];
#pragma unroll
  for (int u = 0; u < 2; ++u)
#pragma unroll
    for (int nt = 0; nt < 4; ++nt) oacc[u][nt] = (f32x4){0.f,0.f,0.f,0.f};
  float m_run[2] = {-1e30f, -1e30f}, l_run[2] = {0.f, 0.f};

  const int srow = tid >> 3, scol = (tid & 7) * 8;

  for (int kt = 0; kt < 8; ++kt){
    const int l0 = kt * 64;
    __syncthreads();
#pragma unroll
    for (int r = 0; r < 2; ++r){
      int row = r*32 + srow;
      *(bf16x8*)&Ks[row*72 + scol] = *(const bf16x8*)&kb[(size_t)(l0 + row)*1024 + scol];
      *(f16x8*)&Vs[row*72 + scol]  = *(const f16x8*)&vb[(size_t)row*512 + l0 + scol];
    }
    __syncthreads();

    f32x4 sacc[2][4];
#pragma unroll
    for (int u = 0; u < 2; ++u)
#pragma unroll
      for (int s = 0; s < 4; ++s) sacc[u][s] = (f32x4){0.f,0.f,0.f,0.f};
#pragma unroll
    for (int s = 0; s < 4; ++s){
      bf16x8 kf0 = *(bf16x8*)&Ks[(s*16 + lm)*72 + quad*8];
      bf16x8 kf1 = *(bf16x8*)&Ks[(s*16 + lm)*72 + 32 + quad*8];
#pragma unroll
      for (int u = 0; u < 2; ++u){
        sacc[u][s] = __builtin_amdgcn_mfma_f32_16x16x32_bf16(kf0, qf[u][0], sacc[u][s], 0, 0, 0);
        sacc[u][s] = __builtin_amdgcn_mfma_f32_16x16x32_bf16(kf1, qf[u][1], sacc[u][s], 0, 0, 0);
      }
    }

    f16x4 pf[2][4];
#pragma unroll
    for (int u = 0; u < 2; ++u){
      float tm = -1e30f;
#pragma unroll
      for (int s = 0; s < 4; ++s)
#pragma unroll
        for (int p = 0; p < 4; ++p) tm = fmaxf(tm, sacc[u][s][p]);
      tm = fmaxf(tm, __shfl_xor(tm, 16, 64));
      tm = fmaxf(tm, __shfl_xor(tm, 32, 64));
      float m_new = fmaxf(m_run[u], tm * 0.125f);
      float alpha = __expf(m_run[u] - m_new);
      m_run[u] = m_new;
      l_run[u] *= alpha;
      float ap[4];
#pragma unroll
      for (int p = 0; p < 4; ++p) ap[p] = __shfl(alpha, quad*4 + p, 64);
#pragma unroll
      for (int nt = 0; nt < 4; ++nt){
        oacc[u][nt][0] *= ap[0]; oacc[u][nt][1] *= ap[1];
        oacc[u][nt][2] *= ap[2]; oacc[u][nt][3] *= ap[3];
      }
#pragma unroll
      for (int s = 0; s < 4; ++s)
#pragma unroll
        for (int p = 0; p < 4; ++p){
          float e = __expf(sacc[u][s][p] * 0.125f - m_new);
          l_run[u] += e;
          pf[u][s][p] = (_Float16)e;
        }
    }

#pragma unroll
    for (int s = 0; s < 4; ++s){
#pragma unroll
      for (int nt = 0; nt < 4; ++nt){
        f16x4 vf = *(const f16x4*)&Vs[(size_t)(nt*16 + lm)*72 + s*16 + quad*4];
#pragma unroll
        for (int u = 0; u < 2; ++u)
          oacc[u][nt] = __builtin_amdgcn_mfma_f32_16x16x16f16(pf[u][s], vf, oacc[u][nt], 0, 0, 0);
      }
    }
  }

#pragma unroll
  for (int u = 0; u < 2; ++u){
    float lr = l_run[u];
    lr += __shfl_xor(lr, 16, 64);
    lr += __shfl_xor(lr, 32, 64);
    float rinv = 1.f / lr;
    float rp[4];
#pragma unroll
    for (int p = 0; p < 4; ++p) rp[p] = __shfl(rinv, quad*4 + p, 64);
    const size_t obase = ((size_t)b*2048 + q0 + wave*32 + u*16) * 1024 + h*64;
#pragma unroll
    for (int nt = 0; nt < 4; ++nt)
#pragma unroll
      for (int p = 0; p < 4; ++p){
        int row = quad*4 + p;
        out[obase + (size_t)row*1024 + nt*16 + lm] = f2b(oacc[u][nt][p] * rp[p]);
      }
  }
}

extern "C" void kernel_launch(void* const* d_in, const int* in_sizes, int n_in,
                              void* d_out, int out_size, void* d_ws, size_t ws_size,
                              hipStream_t stream){
  const float* x_q  = (const float*)d_in[0];
  const float* x_kv = (const float*)d_in[1];
  const float* tvec = (const float*)d_in[2];
  const float* Wq   = (const float*)d_in[3];
  const float* bq   = (const float*)d_in[4];
  const float* Wkv  = (const float*)d_in[5];
  const float* bkv  = (const float*)d_in[6];
  const float* Wp   = (const float*)d_in[7];
  const float* bp   = (const float*)d_in[8];
  const float* Wssq = (const float*)d_in[9];
  const float* bssq = (const float*)d_in[10];
  const float* Wssk = (const float*)d_in[11];
  const float* bssk = (const float*)d_in[12];

  char* ws = (char*)d_ws;
  float*          ss_q  = (float*)(ws + 0);                    // 64 KB
  float*          ss_kv = (float*)(ws + 65536);                // 64 KB
  unsigned short* xq    = (unsigned short*)(ws + 131072);      // 32 MB bf16; reused as attn out
  unsigned short* xkv   = (unsigned short*)(ws + 33685504);    // 8 MB bf16
  unsigned short* qbuf  = (unsigned short*)(ws + 42074112);    // 32 MB bf16
  unsigned short* kbuf  = (unsigned short*)(ws + 75628544);    // 8 MB bf16
  _Float16*       vTbuf = (_Float16*)     (ws + 84017152);     // 8 MB f16
  unsigned short* WqT   = (unsigned short*)(ws + 92405760);    // 2 MB bf16
  unsigned short* WkvT  = (unsigned short*)(ws + 94502912);    // 4 MB bf16
  unsigned short* WpT   = (unsigned short*)(ws + 98697216);    // 2 MB bf16

  dim3 blk(256);
  transpose_k<<<dim3(32, 32), blk, 0, stream>>>(Wq,  WqT,  1024, 1024);
  transpose_k<<<dim3(64, 32), blk, 0, stream>>>(Wkv, WkvT, 1024, 2048);
  transpose_k<<<dim3(32, 32), blk, 0, stream>>>(Wp,  WpT,  1024, 1024);

  ss_init_k<<<dim3(128), blk, 0, stream>>>(bssq, bssk, ss_q, ss_kv);
  ss2_k<<<dim3(8, 16, 2), blk, 0, stream>>>(tvec, Wssq, Wssk, ss_q, ss_kv);

  ada_ln_k<<<dim3(16384), blk, 0, stream>>>(x_q,  ss_q,  xq,  2048);
  ada_ln_k<<<dim3(4096),  blk, 0, stream>>>(x_kv, ss_kv, xkv, 512);

  gemm_bt_k<<<dim3(8, 128), blk, 0, stream>>>(xq,  WqT,  bq,  nullptr, qbuf, nullptr, nullptr,
                                              16384, 1024, 1024, 0);
  gemm_bt_k<<<dim3(16, 32), blk, 0, stream>>>(xkv, WkvT, bkv, nullptr, kbuf, nullptr, vTbuf,
                                              4096, 2048, 1024, 2);

  attn_k<<<dim3(16, 16, 8), blk, 0, stream>>>(qbuf, kbuf, vTbuf, xq);

  gemm_bt_k<<<dim3(8, 128), blk, 0, stream>>>(xq, WpT, bp, x_q, nullptr, (float*)d_out, nullptr,
                                              16384, 1024, 1024, 1);
}